// Round 10
// baseline (174.652 us; speedup 1.0000x reference)
//
#include <hip/hip_runtime.h>

typedef unsigned short u16;
typedef __attribute__((ext_vector_type(8))) short bf16x8;
typedef __attribute__((ext_vector_type(4))) float f32x4;

#define LOG2E 1.4426950408889634f

__device__ __forceinline__ float bf2f(u16 v) {
    union { unsigned u; float f; } x; x.u = ((unsigned)v) << 16; return x.f;
}
__device__ __forceinline__ u16 f2bf(float f) {
    union { float f; unsigned u; } x; x.f = f;
    unsigned u = x.u;
    u += 0x7FFFu + ((u >> 16) & 1u);   // round-to-nearest-even
    return (u16)(u >> 16);
}
__device__ __forceinline__ float sigm(float x) {
    return __builtin_amdgcn_rcpf(1.f + __builtin_amdgcn_exp2f(-x * LOG2E));
}
__device__ __forceinline__ float tanh_fast(float y) {
    float e = __builtin_amdgcn_exp2f(y * (2.f * LOG2E));
    return 1.f - 2.f * __builtin_amdgcn_rcpf(e + 1.f);   // saturates to +-1 safely
}
// raw barrier: LDS visibility only, NO vmem drain (keeps prefetch/stores in flight)
#define STEP_BAR() asm volatile("s_waitcnt lgkmcnt(0)\ns_barrier" ::: "memory")

// ---------------------------------------------------------------------------
// K1: time-kernel attention + cross projection.
// Round-10: 1024 threads/block (was 256) -> 4 waves/SIMD so ds_read + trans
// latency is hidden (was 1 wave/SIMD, 7x stall factor). Thread = (qq, d);
// per-thread exp2 count drops 2048 -> 512. float2 staging (bank-conflict-free).
// grid: 256 blocks = 8 b * 32 q-tiles(4).
// ---------------------------------------------------------------------------
__global__ __launch_bounds__(1024)
void k1_attn_cross(const float* __restrict__ x, const float* __restrict__ ts,
                   const float* __restrict__ qy, const float* __restrict__ bww,
                   const float* __restrict__ cw, const float* __restrict__ cb,
                   u16* __restrict__ outb)
{
    const int blk = blockIdx.x;
    const int b   = blk >> 5;
    const int q0  = (blk & 31) * 4;
    const int tid = threadIdx.x;
    const int qq  = tid >> 8;         // 0..3
    const int d   = tid & 255;
    const int dm  = 128 + (d & 127);

    __shared__ __align__(16) float sc[4][512];
    __shared__ __align__(16) float xs[2][2048];
    __shared__ __align__(16) float attn[4][256];

    for (int i = tid; i < 4 * 512; i += 1024) {
        int q_ = i >> 9, s = i & 511;
        float diff = qy[q0 + q_] - ts[b * 512 + s];
        sc[q_][s] = -diff * diff;
    }
    float w  = bww[d];
    float kk = log1pf(expf(w)) * LOG2E;   // exp(sc*bw) == exp2(sc*kk)

    const float* xb = x + (size_t)b * 512 * 256;
    *(float2*)&xs[0][tid * 2] = *(const float2*)&xb[tid * 2];
    __syncthreads();

    float num = 0.f, den = 0.f;
    for (int s0 = 0; s0 < 512; s0 += 8) {
        int cur = (s0 >> 3) & 1;
        if (s0 + 8 < 512)
            *(float2*)&xs[cur ^ 1][tid * 2] = *(const float2*)&xb[(s0 + 8) * 256 + tid * 2];
        #pragma unroll
        for (int ss = 0; ss < 8; ss++) {
            float xv = xs[cur][ss * 256 + d];
            float mv = xs[cur][ss * 256 + dm];   // mask in {0,1}
            float p  = exp2f(sc[qq][s0 + ss] * kk);
            num += p * (mv * xv);
            den += p * mv;
        }
        __syncthreads();
    }
    attn[qq][d] = num / fmaxf(den, 1e-30f);
    __syncthreads();

    // cross: acc = cb[d] + sum_k attn[qq][k] * cw[d,k]
    float acc = cb[d];
    const float* wr = cw + (size_t)d * 256;
    const float* ar = attn[qq];
    #pragma unroll 4
    for (int k0 = 0; k0 < 256; k0 += 4) {
        float4 wv = *(const float4*)&wr[k0];
        float4 av = *(const float4*)&ar[k0];
        acc += wv.x * av.x + wv.y * av.y + wv.z * av.z + wv.w * av.w;
    }
    outb[(size_t)(b * 128 + q0 + qq) * 256 + d] = f2bf(acc);
}

// ---------------------------------------------------------------------------
// K2: xp via MFMA, gate-consumption layout XP2[z][tau][g][dim][b] bf16,
// tau = (z ? 127-t : t). (unchanged)
// ---------------------------------------------------------------------------
__global__ __launch_bounds__(256)
void k2_xp(const u16* __restrict__ outb,
           const float* __restrict__ wf, const float* __restrict__ bf_,
           const float* __restrict__ wb, const float* __restrict__ bb_,
           u16* __restrict__ xp2)    // [2][128][3][128][8] bf16
{
    const int wid  = threadIdx.x >> 6;
    const int lane = threadIdx.x & 63;
    int gw = blockIdx.x * 4 + wid;
    int z  = (gw >= 1536) ? 1 : 0;
    int t  = gw - z * 1536;
    int rt = t / 24, nt = t - rt * 24;
    int r0 = rt * 16, n0 = nt * 16;

    const float* W  = z ? wb  : wf;
    const float* Bv = z ? bb_ : bf_;

    const u16*   arow = outb + (size_t)(r0 + (lane & 15)) * 256 + (lane >> 4) * 8;
    const float* brow = W    + (size_t)(n0 + (lane & 15)) * 256 + (lane >> 4) * 8;

    f32x4 acc = {0.f, 0.f, 0.f, 0.f};
    #pragma unroll
    for (int k = 0; k < 8; k++) {
        bf16x8 a = *(const bf16x8*)(arow + k * 32);
        float4 w0 = *(const float4*)(brow + k * 32);
        float4 w1 = *(const float4*)(brow + k * 32 + 4);
        bf16x8 bfrag;
        bfrag[0] = (short)f2bf(w0.x); bfrag[1] = (short)f2bf(w0.y);
        bfrag[2] = (short)f2bf(w0.z); bfrag[3] = (short)f2bf(w0.w);
        bfrag[4] = (short)f2bf(w1.x); bfrag[5] = (short)f2bf(w1.y);
        bfrag[6] = (short)f2bf(w1.z); bfrag[7] = (short)f2bf(w1.w);
        acc = __builtin_amdgcn_mfma_f32_16x16x32_bf16(a, bfrag, acc, 0, 0, 0);
    }
    int col   = n0 + (lane & 15);
    int rbase = r0 + (lane >> 4) * 4;
    float bias = Bv[col];
    int g  = col >> 7;
    int dv = col & 127;
    u16* xpz = xp2 + (size_t)z * 393216;
    #pragma unroll
    for (int i = 0; i < 4; i++) {
        int r  = rbase + i;
        int bb = r >> 7;
        int tt = r & 127;
        int tau = z ? (127 - tt) : tt;
        xpz[((size_t)(tau * 3 + g) * 128 + dv) * 8 + bb] = f2bf(acc[i] + bias);
    }
}

// ---------------------------------------------------------------------------
// K3: bidirectional GRU, 8 blocks = (dir z, batch-pair bp), 512 thr (8 waves).
// (unchanged from round 9)
// ---------------------------------------------------------------------------
#define K3_STEP(T, XR, XZ, XN) {                                              \
    const int rslot = ((T) + 1) & 1, wslot = (T) & 1;                         \
    bf16x8 A0 = {0,0,0,0,0,0,0,0}, A1 = {0,0,0,0,0,0,0,0};                    \
    bf16x8 A2 = {0,0,0,0,0,0,0,0}, A3 = {0,0,0,0,0,0,0,0};                    \
    if ((nr & 3) == 0 && nr < 8) {   /* rows 0,4 hold batches 0,1 */          \
        const u16* hb_ = &hist[rslot][nr >> 2][0];                            \
        A0 = *(const bf16x8*)&hb_[kb];                                        \
        A1 = *(const bf16x8*)&hb_[32 + kb];                                   \
        A2 = *(const bf16x8*)&hb_[64 + kb];                                   \
        A3 = *(const bf16x8*)&hb_[96 + kb];                                   \
    }                                                                         \
    f32x4 a0 = {0.f,0.f,0.f,0.f}, a1 = a0, a2 = a0;                           \
    a0 = __builtin_amdgcn_mfma_f32_16x16x32_bf16(A0, Whi[0][0], a0, 0,0,0);   \
    a1 = __builtin_amdgcn_mfma_f32_16x16x32_bf16(A0, Whi[1][0], a1, 0,0,0);   \
    a2 = __builtin_amdgcn_mfma_f32_16x16x32_bf16(A0, Whi[2][0], a2, 0,0,0);   \
    a0 = __builtin_amdgcn_mfma_f32_16x16x32_bf16(A1, Whi[0][1], a0, 0,0,0);   \
    a1 = __builtin_amdgcn_mfma_f32_16x16x32_bf16(A1, Whi[1][1], a1, 0,0,0);   \
    a2 = __builtin_amdgcn_mfma_f32_16x16x32_bf16(A1, Whi[2][1], a2, 0,0,0);   \
    a0 = __builtin_amdgcn_mfma_f32_16x16x32_bf16(A2, Whi[0][2], a0, 0,0,0);   \
    a1 = __builtin_amdgcn_mfma_f32_16x16x32_bf16(A2, Whi[1][2], a1, 0,0,0);   \
    a2 = __builtin_amdgcn_mfma_f32_16x16x32_bf16(A2, Whi[2][2], a2, 0,0,0);   \
    a0 = __builtin_amdgcn_mfma_f32_16x16x32_bf16(A3, Whi[0][3], a0, 0,0,0);   \
    a1 = __builtin_amdgcn_mfma_f32_16x16x32_bf16(A3, Whi[1][3], a1, 0,0,0);   \
    a2 = __builtin_amdgcn_mfma_f32_16x16x32_bf16(A3, Whi[2][3], a2, 0,0,0);   \
    if (l < 32) {                                                             \
        const int tw = z ? (127 - (T)) : (T);                                 \
        float rr = sigm(bf2f(XR) + a0[0] + br);                               \
        float zg = sigm(bf2f(XZ) + a1[0] + bz);                               \
        float nn = tanh_fast(bf2f(XN) + rr * (a2[0] + bn));                   \
        hm = (1.f - zg) * nn + zg * hm;                                       \
        u16 hb = f2bf(hm);                                                    \
        hist[wslot][gm][gdim] = hb;                                           \
        ho[(size_t)gm * 16384 + (size_t)tw * 128 + gdim] = hb;                \
        int t2 = (T) + 2; if (t2 > 127) t2 = 127;                             \
        XR = xpz[((size_t)(t2 * 3 + 0) * 128 + gdim) * 8 + gm];               \
        XZ = xpz[((size_t)(t2 * 3 + 1) * 128 + gdim) * 8 + gm];               \
        XN = xpz[((size_t)(t2 * 3 + 2) * 128 + gdim) * 8 + gm];               \
    }                                                                         \
    STEP_BAR();                                                               \
}

__global__ __launch_bounds__(512)
void k3_gru(const u16* __restrict__ xp2,      // [2][128][3][128][8] bf16
            const float* __restrict__ whf, const float* __restrict__ bhf,
            const float* __restrict__ whb, const float* __restrict__ bhb,
            u16* __restrict__ hout)           // [2][8][128][128] bf16
{
    const int z   = blockIdx.x >> 2;
    const int bp  = blockIdx.x & 3;           // batches 2bp, 2bp+1
    const int tid = threadIdx.x;
    const int w   = tid >> 6;
    const int l   = tid & 63;
    const int nr  = l & 15;
    const int kb  = (l >> 4) * 8;
    const int gm   = l >> 4;                  // gate batch (valid l<32)
    const int gdim = w * 16 + (l & 15);       // gate hidden dim (valid l<32)

    __shared__ __align__(16) u16 hist[2][2][128];   // [slot][m][hidden] 1 KB

    const float* W  = z ? whb : whf;
    const float* bh = z ? bhb : bhf;

    // W_hh B-frags (bf16) in VGPRs: wave w owns n-tiles {w, w+8, w+16}
    bf16x8 Whi[3][4];
    #pragma unroll
    for (int g = 0; g < 3; g++) {
        #pragma unroll
        for (int kt = 0; kt < 4; kt++) {
            const float* src = W + (size_t)(g * 128 + w * 16 + nr) * 128 + kt * 32 + kb;
            float4 w0 = *(const float4*)src;
            float4 w1 = *(const float4*)(src + 4);
            bf16x8 hi;
            hi[0] = (short)f2bf(w0.x); hi[1] = (short)f2bf(w0.y);
            hi[2] = (short)f2bf(w0.z); hi[3] = (short)f2bf(w0.w);
            hi[4] = (short)f2bf(w1.x); hi[5] = (short)f2bf(w1.y);
            hi[6] = (short)f2bf(w1.z); hi[7] = (short)f2bf(w1.w);
            Whi[g][kt] = hi;
        }
    }

    float br = 0.f, bz = 0.f, bn = 0.f;
    float hm = 0.f;
    const u16* xpz = xp2 + (size_t)z * 393216 + 2 * bp;   // +gm per lane
    u16* ho = hout + (size_t)z * 131072 + (size_t)(2 * bp) * 16384;

    u16 xAr = 0, xAz = 0, xAn = 0, xBr = 0, xBz = 0, xBn = 0;
    if (l < 32) {
        br = bh[gdim]; bz = bh[gdim + 128]; bn = bh[gdim + 256];
        xAr = xpz[((size_t)(0 * 3 + 0) * 128 + gdim) * 8 + gm];
        xAz = xpz[((size_t)(0 * 3 + 1) * 128 + gdim) * 8 + gm];
        xAn = xpz[((size_t)(0 * 3 + 2) * 128 + gdim) * 8 + gm];
        xBr = xpz[((size_t)(1 * 3 + 0) * 128 + gdim) * 8 + gm];
        xBz = xpz[((size_t)(1 * 3 + 1) * 128 + gdim) * 8 + gm];
        xBn = xpz[((size_t)(1 * 3 + 2) * 128 + gdim) * 8 + gm];
    }
    if (tid < 256) ((unsigned*)hist)[tid] = 0u;    // h = 0 (both slots)
    __syncthreads();

    for (int c = 0; c < 64; c++) {
        K3_STEP(2 * c,     xAr, xAz, xAn)
        K3_STEP(2 * c + 1, xBr, xBz, xBn)
    }
}

// ---------------------------------------------------------------------------
// K4: MLP head. 1024 blocks = (b,t), 128 threads. (unchanged)
// ---------------------------------------------------------------------------
__global__ __launch_bounds__(128)
void k4_mlp(const u16* __restrict__ hout,
            const float* __restrict__ w1, const float* __restrict__ b1,
            const float* __restrict__ w2, const float* __restrict__ b2,
            float* __restrict__ out)
{
    const int bq  = blockIdx.x;
    const int tid = threadIdx.x;

    __shared__ __align__(16) float hrow[256];
    __shared__ float hid[50];

    const u16* hf = hout + (size_t)bq * 128;
    const u16* hb = hout + (size_t)8 * 128 * 128 + (size_t)bq * 128;
    hrow[tid]       = bf2f(hf[tid]);
    hrow[128 + tid] = bf2f(hb[tid]);
    __syncthreads();

    if (tid < 50) {
        float a = b1[tid];
        const float* wr = w1 + (size_t)tid * 256;
        for (int k0 = 0; k0 < 256; k0 += 8) {
            float4 wv0 = *(const float4*)&wr[k0];
            float4 wv1 = *(const float4*)&wr[k0 + 4];
            float4 h0  = *(const float4*)&hrow[k0];
            float4 h1  = *(const float4*)&hrow[k0 + 4];
            a += wv0.x * h0.x + wv0.y * h0.y + wv0.z * h0.z + wv0.w * h0.w;
            a += wv1.x * h1.x + wv1.y * h1.y + wv1.z * h1.z + wv1.w * h1.w;
        }
        hid[tid] = fmaxf(a, 0.f);
    }
    __syncthreads();
    if (tid < 64) {
        float a = b2[tid];
        const float* wr = w2 + (size_t)tid * 50;
        for (int k = 0; k < 50; k++) a += wr[k] * hid[k];
        out[(size_t)bq * 64 + tid] = a;
    }
}

// ---------------------------------------------------------------------------
// Workspace (2.0 MB): [0,512K) outb (K1->K2), reused as hout (K3->K4);
//                     [512K,2.0M) XP2 (K2->K3, gate-consumption layout).
// ---------------------------------------------------------------------------
extern "C" void kernel_launch(void* const* d_in, const int* in_sizes, int n_in,
                              void* d_out, int out_size, void* d_ws, size_t ws_size,
                              hipStream_t stream)
{
    const float* x    = (const float*)d_in[0];
    const float* ts   = (const float*)d_in[1];
    const float* qy   = (const float*)d_in[2];
    const float* bww  = (const float*)d_in[3];
    const float* cw   = (const float*)d_in[4];
    const float* cb   = (const float*)d_in[5];
    const float* wihf = (const float*)d_in[6];
    const float* whhf = (const float*)d_in[7];
    const float* bihf = (const float*)d_in[8];
    const float* bhhf = (const float*)d_in[9];
    const float* wihb = (const float*)d_in[10];
    const float* whhb = (const float*)d_in[11];
    const float* bihb = (const float*)d_in[12];
    const float* bhhb = (const float*)d_in[13];
    const float* w1   = (const float*)d_in[14];
    const float* b1   = (const float*)d_in[15];
    const float* w2   = (const float*)d_in[16];
    const float* b2   = (const float*)d_in[17];
    float* out = (float*)d_out;

    char* ws = (char*)d_ws;
    u16* outb = (u16*)ws;                     // 512 KB
    u16* hout = (u16*)ws;                     // alias (outb dead after K2)
    u16* xp2  = (u16*)(ws + 512 * 1024);      // 1.5 MB

    k1_attn_cross<<<256, 1024, 0, stream>>>(x, ts, qy, bww, cw, cb, outb);
    k2_xp<<<768, 256, 0, stream>>>(outb, wihf, bihf, wihb, bihb, xp2);
    k3_gru<<<8, 512, 0, stream>>>(xp2, whhf, bhhf, whhb, bhhb, hout);
    k4_mlp<<<1024, 128, 0, stream>>>(hout, w1, b1, w2, b2, out);
}

// Round 11
// 128.571 us; speedup vs baseline: 1.3584x; 1.3584x over previous
//
#include <hip/hip_runtime.h>

typedef unsigned short u16;
typedef __attribute__((ext_vector_type(8))) short bf16x8;
typedef __attribute__((ext_vector_type(4))) float f32x4;

#define LOG2E 1.4426950408889634f

__device__ __forceinline__ float bf2f(u16 v) {
    union { unsigned u; float f; } x; x.u = ((unsigned)v) << 16; return x.f;
}
__device__ __forceinline__ u16 f2bf(float f) {
    union { float f; unsigned u; } x; x.f = f;
    unsigned u = x.u;
    u += 0x7FFFu + ((u >> 16) & 1u);   // round-to-nearest-even
    return (u16)(u >> 16);
}
__device__ __forceinline__ float sigm(float x) {
    return __builtin_amdgcn_rcpf(1.f + __builtin_amdgcn_exp2f(-x * LOG2E));
}
__device__ __forceinline__ float tanh_fast(float y) {
    float e = __builtin_amdgcn_exp2f(y * (2.f * LOG2E));
    return 1.f - 2.f * __builtin_amdgcn_rcpf(e + 1.f);   // saturates to +-1 safely
}
// raw barrier: LDS visibility only, NO vmem drain
#define STEP_BAR() asm volatile("s_waitcnt lgkmcnt(0)\ns_barrier" ::: "memory")

// ---------------------------------------------------------------------------
// K0: fold cross projection into the GRU input weights (algebraic fusion):
//   xp = (A @ cw^T + cb) @ wih^T + bih  ==  A @ Wf^T + Bf
//   Wf[z][n][j] = sum_k wih_z[n][k] * cw[k][j]   (bf16)
//   Bf[z][n]    = sum_k wih_z[n][k] * cb[k] + bih_z[n]
// grid: 192 blocks = 2 dirs x 48 row-quads... (z = blk/96, 4 rows each), 256 thr.
// ---------------------------------------------------------------------------
__global__ __launch_bounds__(256)
void k0_fuse(const float* __restrict__ wihf, const float* __restrict__ bihf,
             const float* __restrict__ wihb, const float* __restrict__ bihb,
             const float* __restrict__ cw, const float* __restrict__ cb,
             u16* __restrict__ Wf, float* __restrict__ Bf)
{
    const int z  = blockIdx.x / 96;
    const int n0 = (blockIdx.x % 96) * 4;
    const int j  = threadIdx.x;
    const float* W   = z ? wihb : wihf;
    const float* bih = z ? bihb : bihf;

    __shared__ float red[256];

    float a0 = 0.f, a1 = 0.f, a2 = 0.f, a3 = 0.f;
    for (int k = 0; k < 256; k++) {
        float cv = cw[(size_t)k * 256 + j];       // coalesced
        a0 += W[(size_t)(n0 + 0) * 256 + k] * cv; // uniform (s_load)
        a1 += W[(size_t)(n0 + 1) * 256 + k] * cv;
        a2 += W[(size_t)(n0 + 2) * 256 + k] * cv;
        a3 += W[(size_t)(n0 + 3) * 256 + k] * cv;
    }
    u16* wout = Wf + ((size_t)z * 384 + n0) * 256 + j;
    wout[0]   = f2bf(a0);
    wout[256] = f2bf(a1);
    wout[512] = f2bf(a2);
    wout[768] = f2bf(a3);

    float cbv = cb[j];
    #pragma unroll
    for (int i = 0; i < 4; i++) {
        red[j] = W[(size_t)(n0 + i) * 256 + j] * cbv;
        __syncthreads();
        if (j < 64) red[j] += red[j + 64] + red[j + 128] + red[j + 192];
        __syncthreads();
        if (j == 0) {
            float s = 0.f;
            for (int t = 0; t < 64; t++) s += red[t];
            Bf[z * 384 + n0 + i] = s + bih[n0 + i];
        }
        __syncthreads();
    }
}

// ---------------------------------------------------------------------------
// K1: time-kernel attention (cross projection removed -- folded into K0/K2).
// Zero-LDS main loop: exponent arg = A_q + t*(B_q + C*t) from registers;
// x/mask read coalesced from global (L2-resident); ts via scalar loads.
// grid: 256 blocks = (b, qt of 4 q); 1024 thr = (qp, sh, d): 2 q x 256 s each.
// Only LDS: 8 KB num/den half-reduction.
// ---------------------------------------------------------------------------
__global__ __launch_bounds__(1024)
void k1_attn(const float* __restrict__ x, const float* __restrict__ ts,
             const float* __restrict__ qy, const float* __restrict__ bww,
             u16* __restrict__ aout)
{
    const int b   = blockIdx.x >> 5;
    const int q0  = (blockIdx.x & 31) * 4;
    const int tid = threadIdx.x;
    const int d   = tid & 255;
    const int sh  = (tid >> 8) & 1;
    const int qp  = tid >> 9;
    const int dm  = 128 + (d & 127);

    __shared__ float red[4][512];

    float w  = bww[d];
    float kk = log1pf(expf(w)) * LOG2E;     // exp(sc*bw) == exp2(sc*kk)
    float qv0 = qy[q0 + qp * 2], qv1 = qy[q0 + qp * 2 + 1];
    float A0 = -kk * qv0 * qv0, B0 = 2.f * kk * qv0;
    float A1 = -kk * qv1 * qv1, B1 = 2.f * kk * qv1;
    float C  = -kk;

    const float* xb = x + (size_t)b * 512 * 256;
    const float* tb = ts + b * 512;

    float n0 = 0.f, n1 = 0.f, d0 = 0.f, d1 = 0.f;
    const int s0 = sh * 256;
    #pragma unroll 4
    for (int s = s0; s < s0 + 256; s++) {
        float xv = xb[(size_t)s * 256 + d];
        float mv = xb[(size_t)s * 256 + dm];    // mask in {0,1}
        float t  = tb[s];                        // uniform -> s_load
        float ct  = C * t;
        float mxv = mv * xv;
        float p0 = __builtin_amdgcn_exp2f(A0 + t * (B0 + ct));
        float p1 = __builtin_amdgcn_exp2f(A1 + t * (B1 + ct));
        n0 += p0 * mxv;  d0 += p0 * mv;
        n1 += p1 * mxv;  d1 += p1 * mv;
    }

    if (sh == 1) {
        int u = qp * 256 + d;
        red[0][u] = n0; red[1][u] = n1; red[2][u] = d0; red[3][u] = d1;
    }
    __syncthreads();
    if (sh == 0) {
        int u = qp * 256 + d;
        n0 += red[0][u]; n1 += red[1][u]; d0 += red[2][u]; d1 += red[3][u];
        float r0 = n0 / fmaxf(d0, 1e-30f);
        float r1 = n1 / fmaxf(d1, 1e-30f);
        aout[(size_t)(b * 128 + q0 + qp * 2 + 0) * 256 + d] = f2bf(r0);
        aout[(size_t)(b * 128 + q0 + qp * 2 + 1) * 256 + d] = f2bf(r1);
    }
}

// ---------------------------------------------------------------------------
// K2: xp2 = aout @ Wf^T + Bf via MFMA 16x16x32 bf16 (weights pre-fused bf16).
// Gate-consumption layout XP2[z][tau][g][dim][b], tau = (z ? 127-t : t).
// ---------------------------------------------------------------------------
__global__ __launch_bounds__(256)
void k2_xp(const u16* __restrict__ aout,
           const u16* __restrict__ Wf, const float* __restrict__ Bf,
           u16* __restrict__ xp2)    // [2][128][3][128][8] bf16
{
    const int wid  = threadIdx.x >> 6;
    const int lane = threadIdx.x & 63;
    int gw = blockIdx.x * 4 + wid;
    int z  = (gw >= 1536) ? 1 : 0;
    int t  = gw - z * 1536;
    int rt = t / 24, nt = t - rt * 24;
    int r0 = rt * 16, n0 = nt * 16;

    const u16*   W  = Wf + (size_t)z * 384 * 256;
    const float* Bv = Bf + z * 384;

    const u16* arow = aout + (size_t)(r0 + (lane & 15)) * 256 + (lane >> 4) * 8;
    const u16* brow = W    + (size_t)(n0 + (lane & 15)) * 256 + (lane >> 4) * 8;

    f32x4 acc = {0.f, 0.f, 0.f, 0.f};
    #pragma unroll
    for (int k = 0; k < 8; k++) {
        bf16x8 a     = *(const bf16x8*)(arow + k * 32);
        bf16x8 bfrag = *(const bf16x8*)(brow + k * 32);
        acc = __builtin_amdgcn_mfma_f32_16x16x32_bf16(a, bfrag, acc, 0, 0, 0);
    }
    int col   = n0 + (lane & 15);
    int rbase = r0 + (lane >> 4) * 4;
    float bias = Bv[col];
    int g  = col >> 7;
    int dv = col & 127;
    u16* xpz = xp2 + (size_t)z * 393216;
    #pragma unroll
    for (int i = 0; i < 4; i++) {
        int r  = rbase + i;
        int bb = r >> 7;
        int tt = r & 127;
        int tau = z ? (127 - tt) : tt;
        xpz[((size_t)(tau * 3 + g) * 128 + dv) * 8 + bb] = f2bf(acc[i] + bias);
    }
}

// ---------------------------------------------------------------------------
// K3: bidirectional GRU, 8 blocks = (dir z, batch-pair bp), 512 thr (8 waves).
// (unchanged from round 9/10)
// ---------------------------------------------------------------------------
#define K3_STEP(T, XR, XZ, XN) {                                              \
    const int rslot = ((T) + 1) & 1, wslot = (T) & 1;                         \
    bf16x8 A0 = {0,0,0,0,0,0,0,0}, A1 = {0,0,0,0,0,0,0,0};                    \
    bf16x8 A2 = {0,0,0,0,0,0,0,0}, A3 = {0,0,0,0,0,0,0,0};                    \
    if ((nr & 3) == 0 && nr < 8) {   /* rows 0,4 hold batches 0,1 */          \
        const u16* hb_ = &hist[rslot][nr >> 2][0];                            \
        A0 = *(const bf16x8*)&hb_[kb];                                        \
        A1 = *(const bf16x8*)&hb_[32 + kb];                                   \
        A2 = *(const bf16x8*)&hb_[64 + kb];                                   \
        A3 = *(const bf16x8*)&hb_[96 + kb];                                   \
    }                                                                         \
    f32x4 a0 = {0.f,0.f,0.f,0.f}, a1 = a0, a2 = a0;                           \
    a0 = __builtin_amdgcn_mfma_f32_16x16x32_bf16(A0, Whi[0][0], a0, 0,0,0);   \
    a1 = __builtin_amdgcn_mfma_f32_16x16x32_bf16(A0, Whi[1][0], a1, 0,0,0);   \
    a2 = __builtin_amdgcn_mfma_f32_16x16x32_bf16(A0, Whi[2][0], a2, 0,0,0);   \
    a0 = __builtin_amdgcn_mfma_f32_16x16x32_bf16(A1, Whi[0][1], a0, 0,0,0);   \
    a1 = __builtin_amdgcn_mfma_f32_16x16x32_bf16(A1, Whi[1][1], a1, 0,0,0);   \
    a2 = __builtin_amdgcn_mfma_f32_16x16x32_bf16(A1, Whi[2][1], a2, 0,0,0);   \
    a0 = __builtin_amdgcn_mfma_f32_16x16x32_bf16(A2, Whi[0][2], a0, 0,0,0);   \
    a1 = __builtin_amdgcn_mfma_f32_16x16x32_bf16(A2, Whi[1][2], a1, 0,0,0);   \
    a2 = __builtin_amdgcn_mfma_f32_16x16x32_bf16(A2, Whi[2][2], a2, 0,0,0);   \
    a0 = __builtin_amdgcn_mfma_f32_16x16x32_bf16(A3, Whi[0][3], a0, 0,0,0);   \
    a1 = __builtin_amdgcn_mfma_f32_16x16x32_bf16(A3, Whi[1][3], a1, 0,0,0);   \
    a2 = __builtin_amdgcn_mfma_f32_16x16x32_bf16(A3, Whi[2][3], a2, 0,0,0);   \
    if (l < 32) {                                                             \
        const int tw = z ? (127 - (T)) : (T);                                 \
        float rr = sigm(bf2f(XR) + a0[0] + br);                               \
        float zg = sigm(bf2f(XZ) + a1[0] + bz);                               \
        float nn = tanh_fast(bf2f(XN) + rr * (a2[0] + bn));                   \
        hm = (1.f - zg) * nn + zg * hm;                                       \
        u16 hb = f2bf(hm);                                                    \
        hist[wslot][gm][gdim] = hb;                                           \
        ho[(size_t)gm * 16384 + (size_t)tw * 128 + gdim] = hb;                \
        int t2 = (T) + 2; if (t2 > 127) t2 = 127;                             \
        XR = xpz[((size_t)(t2 * 3 + 0) * 128 + gdim) * 8 + gm];               \
        XZ = xpz[((size_t)(t2 * 3 + 1) * 128 + gdim) * 8 + gm];               \
        XN = xpz[((size_t)(t2 * 3 + 2) * 128 + gdim) * 8 + gm];               \
    }                                                                         \
    STEP_BAR();                                                               \
}

__global__ __launch_bounds__(512)
void k3_gru(const u16* __restrict__ xp2,      // [2][128][3][128][8] bf16
            const float* __restrict__ whf, const float* __restrict__ bhf,
            const float* __restrict__ whb, const float* __restrict__ bhb,
            u16* __restrict__ hout)           // [2][8][128][128] bf16
{
    const int z   = blockIdx.x >> 2;
    const int bp  = blockIdx.x & 3;           // batches 2bp, 2bp+1
    const int tid = threadIdx.x;
    const int w   = tid >> 6;
    const int l   = tid & 63;
    const int nr  = l & 15;
    const int kb  = (l >> 4) * 8;
    const int gm   = l >> 4;                  // gate batch (valid l<32)
    const int gdim = w * 16 + (l & 15);       // gate hidden dim (valid l<32)

    __shared__ __align__(16) u16 hist[2][2][128];   // [slot][m][hidden] 1 KB

    const float* W  = z ? whb : whf;
    const float* bh = z ? bhb : bhf;

    // W_hh B-frags (bf16) in VGPRs: wave w owns n-tiles {w, w+8, w+16}
    bf16x8 Whi[3][4];
    #pragma unroll
    for (int g = 0; g < 3; g++) {
        #pragma unroll
        for (int kt = 0; kt < 4; kt++) {
            const float* src = W + (size_t)(g * 128 + w * 16 + nr) * 128 + kt * 32 + kb;
            float4 w0 = *(const float4*)src;
            float4 w1 = *(const float4*)(src + 4);
            bf16x8 hi;
            hi[0] = (short)f2bf(w0.x); hi[1] = (short)f2bf(w0.y);
            hi[2] = (short)f2bf(w0.z); hi[3] = (short)f2bf(w0.w);
            hi[4] = (short)f2bf(w1.x); hi[5] = (short)f2bf(w1.y);
            hi[6] = (short)f2bf(w1.z); hi[7] = (short)f2bf(w1.w);
            Whi[g][kt] = hi;
        }
    }

    float br = 0.f, bz = 0.f, bn = 0.f;
    float hm = 0.f;
    const u16* xpz = xp2 + (size_t)z * 393216 + 2 * bp;   // +gm per lane
    u16* ho = hout + (size_t)z * 131072 + (size_t)(2 * bp) * 16384;

    u16 xAr = 0, xAz = 0, xAn = 0, xBr = 0, xBz = 0, xBn = 0;
    if (l < 32) {
        br = bh[gdim]; bz = bh[gdim + 128]; bn = bh[gdim + 256];
        xAr = xpz[((size_t)(0 * 3 + 0) * 128 + gdim) * 8 + gm];
        xAz = xpz[((size_t)(0 * 3 + 1) * 128 + gdim) * 8 + gm];
        xAn = xpz[((size_t)(0 * 3 + 2) * 128 + gdim) * 8 + gm];
        xBr = xpz[((size_t)(1 * 3 + 0) * 128 + gdim) * 8 + gm];
        xBz = xpz[((size_t)(1 * 3 + 1) * 128 + gdim) * 8 + gm];
        xBn = xpz[((size_t)(1 * 3 + 2) * 128 + gdim) * 8 + gm];
    }
    if (tid < 256) ((unsigned*)hist)[tid] = 0u;    // h = 0 (both slots)
    __syncthreads();

    for (int c = 0; c < 64; c++) {
        K3_STEP(2 * c,     xAr, xAz, xAn)
        K3_STEP(2 * c + 1, xBr, xBz, xBn)
    }
}

// ---------------------------------------------------------------------------
// K4: MLP head. 1024 blocks = (b,t), 128 threads. (unchanged)
// ---------------------------------------------------------------------------
__global__ __launch_bounds__(128)
void k4_mlp(const u16* __restrict__ hout,
            const float* __restrict__ w1, const float* __restrict__ b1,
            const float* __restrict__ w2, const float* __restrict__ b2,
            float* __restrict__ out)
{
    const int bq  = blockIdx.x;
    const int tid = threadIdx.x;

    __shared__ __align__(16) float hrow[256];
    __shared__ float hid[50];

    const u16* hf = hout + (size_t)bq * 128;
    const u16* hb = hout + (size_t)8 * 128 * 128 + (size_t)bq * 128;
    hrow[tid]       = bf2f(hf[tid]);
    hrow[128 + tid] = bf2f(hb[tid]);
    __syncthreads();

    if (tid < 50) {
        float a = b1[tid];
        const float* wr = w1 + (size_t)tid * 256;
        for (int k0 = 0; k0 < 256; k0 += 8) {
            float4 wv0 = *(const float4*)&wr[k0];
            float4 wv1 = *(const float4*)&wr[k0 + 4];
            float4 h0  = *(const float4*)&hrow[k0];
            float4 h1  = *(const float4*)&hrow[k0 + 4];
            a += wv0.x * h0.x + wv0.y * h0.y + wv0.z * h0.z + wv0.w * h0.w;
            a += wv1.x * h1.x + wv1.y * h1.y + wv1.z * h1.z + wv1.w * h1.w;
        }
        hid[tid] = fmaxf(a, 0.f);
    }
    __syncthreads();
    if (tid < 64) {
        float a = b2[tid];
        const float* wr = w2 + (size_t)tid * 50;
        for (int k = 0; k < 50; k++) a += wr[k] * hid[k];
        out[(size_t)bq * 64 + tid] = a;
    }
}

// ---------------------------------------------------------------------------
// Workspace (2.4 MB):
//   [0,     512K) : aout bf16 (K1->K2), reused as hout (K3->K4)
//   [512K,  2.0M) : xp2 bf16 (K2->K3)
//   [2.0M,  2.375M): Wf bf16 [2][384][256] (K0->K2)
//   [2.375M,+3K)  : Bf f32  [2][384]      (K0->K2)
// ---------------------------------------------------------------------------
extern "C" void kernel_launch(void* const* d_in, const int* in_sizes, int n_in,
                              void* d_out, int out_size, void* d_ws, size_t ws_size,
                              hipStream_t stream)
{
    const float* x    = (const float*)d_in[0];
    const float* ts   = (const float*)d_in[1];
    const float* qy   = (const float*)d_in[2];
    const float* bww  = (const float*)d_in[3];
    const float* cw   = (const float*)d_in[4];
    const float* cb   = (const float*)d_in[5];
    const float* wihf = (const float*)d_in[6];
    const float* whhf = (const float*)d_in[7];
    const float* bihf = (const float*)d_in[8];
    const float* bhhf = (const float*)d_in[9];
    const float* wihb = (const float*)d_in[10];
    const float* whhb = (const float*)d_in[11];
    const float* bihb = (const float*)d_in[12];
    const float* bhhb = (const float*)d_in[13];
    const float* w1   = (const float*)d_in[14];
    const float* b1   = (const float*)d_in[15];
    const float* w2   = (const float*)d_in[16];
    const float* b2   = (const float*)d_in[17];
    float* out = (float*)d_out;

    char* ws = (char*)d_ws;
    u16*   aout = (u16*)ws;                            // 512 KB
    u16*   hout = (u16*)ws;                            // alias (aout dead after K2)
    u16*   xp2  = (u16*)(ws + (512 << 10));            // 1.5 MB
    u16*   Wf   = (u16*)(ws + (2u << 20));             // 384 KB
    float* Bf   = (float*)(ws + (2u << 20) + 384 * 1024);  // 3 KB

    k0_fuse<<<192, 256, 0, stream>>>(wihf, bihf, wihb, bihb, cw, cb, Wf, Bf);
    k1_attn<<<256, 1024, 0, stream>>>(x, ts, qy, bww, aout);
    k2_xp<<<768, 256, 0, stream>>>(aout, Wf, Bf, xp2);
    k3_gru<<<8, 512, 0, stream>>>(xp2, whhf, bhhf, whhb, bhhb, hout);
    k4_mlp<<<1024, 128, 0, stream>>>(hout, w1, b1, w2, b2, out);
}